// Round 24
// baseline (785.674 us; speedup 1.0000x reference)
//
#include <hip/hip_runtime.h>
#include <hip/hip_bf16.h>
#include <math.h>

#define CH 128
#define KSEL 512
#define CAP 4096
#define TOT 2048   // 4*KSEL
#define TS 32      // NMS tile
#define NEG_INF (-__builtin_inff())

typedef short s8v __attribute__((ext_vector_type(8)));    // 8 bf16 (4 VGPRs)
typedef float f16v __attribute__((ext_vector_type(16)));  // 32x32 MFMA acc

__device__ __forceinline__ float gelu_exact(float v) {
    return v * 0.5f * (1.0f + erff(v * 0.70710678118654752440f));
}

// exact 3-plane bf16 split via HW cvt (R23-verified): v = h + m + l + O(2^-24 v)
__device__ __forceinline__ void split3(float v, unsigned short& h,
                                       unsigned short& m, unsigned short& l)
{
    union BU { __hip_bfloat16 b; unsigned short u; };
    __hip_bfloat16 hb = __float2bfloat16(v);
    BU x; x.b = hb; h = x.u;
    float r1 = v - __bfloat162float(hb);
    __hip_bfloat16 mb = __float2bfloat16(r1);
    BU y; y.b = mb; m = y.u;
    float r2 = r1 - __bfloat162float(mb);
    __hip_bfloat16 lb = __float2bfloat16(r2);
    BU z; z.b = lb; l = z.u;
}

// ---------------- W1 -> 3-plane bf16 A-fragments for 32x32x16 ----------------
// frag f = (g*8 + kc)*3 + plane (g = och>>5); u16 idx = f*512 + lane*8 + e
// A[och = g*32 + (lane&31)][k = kc*16 + ((lane>>5)<<3) + e]   (symmetric k-map)
__global__ __launch_bounds__(256) void wconv_kernel(const float* __restrict__ w1,
                                                    unsigned short* __restrict__ wfrag)
{
    for (int ei = blockIdx.x * 256 + threadIdx.x; ei < 49152; ei += gridDim.x * 256) {
        int f = ei >> 9;
        int r = ei & 511;
        int lane = r >> 3;
        int e = r & 7;
        int plane = f % 3;
        int fq = f / 3;
        int g = fq >> 3, kc = fq & 7;
        int och = g * 32 + (lane & 31);
        int k = kc * 16 + ((lane >> 5) << 3) + e;
        unsigned short h, m, l;
        split3(w1[och * CH + k], h, m, l);
        wfrag[ei] = (plane == 0) ? h : (plane == 1) ? m : l;
    }
}

// ---------------- reliability head: 32x32x16 MFMA, W in REGISTERS ----------------
// 256 thr / 4 waves; wave w owns och group w (32 och), all share one 32-px tile.
// W frags: 24 x s8v = 96 VGPR persistent; acc = 16 AGPR; LDS ~1.5KB -> occupancy
// is register-bound only (~3 waves/SIMD vs R23's 2). kc loop is REAL (unroll 1,
// R14) with switch(kc) so frag refs stay statically indexed (no scratch).
// C/D map (HW-verified m74/m101): col = lane&31 (px), row = (reg&3)+8*(reg>>2)+4*(lane>>5).
__global__ __launch_bounds__(256) void rel_mfma_kernel(
    const float* __restrict__ fm0, const float* __restrict__ fm1,
    const float* __restrict__ fm2, const float* __restrict__ fm3,
    const unsigned short* __restrict__ wfrag,
    const float* __restrict__ b1, const float* __restrict__ w2,
    const float* __restrict__ b2, float* __restrict__ rel)
{
    __shared__ float w2s[128], b1s[128];
    __shared__ float partLds[4][32];

    const int tid = threadIdx.x;
    const int lane = tid & 63;
    const int w = tid >> 6;                 // och group 0..3
    if (tid < 128) { w2s[tid] = w2[tid]; b1s[tid] = b1[tid]; }
    __syncthreads();

    // load this wave's 24 W fragments (och group w), once
    #define WLD(KC, PL) (*(const s8v*)(wfrag + (((w * 8 + (KC)) * 3 + (PL)) << 9) + (lane << 3)))
    s8v a0h = WLD(0,0), a0m = WLD(0,1), a0l = WLD(0,2);
    s8v a1h = WLD(1,0), a1m = WLD(1,1), a1l = WLD(1,2);
    s8v a2h = WLD(2,0), a2m = WLD(2,1), a2l = WLD(2,2);
    s8v a3h = WLD(3,0), a3m = WLD(3,1), a3l = WLD(3,2);
    s8v a4h = WLD(4,0), a4m = WLD(4,1), a4l = WLD(4,2);
    s8v a5h = WLD(5,0), a5m = WLD(5,1), a5l = WLD(5,2);
    s8v a6h = WLD(6,0), a6m = WLD(6,1), a6l = WLD(6,2);
    s8v a7h = WLD(7,0), a7m = WLD(7,1), a7l = WLD(7,2);
    #undef WLD

    const float* fms[4] = {fm0, fm1, fm2, fm3};
    // 32-px tiles: s0 16384, s1 4096, s2 1024, s3 256 -> total 21760
    const int pre1 = 16384, pre2 = 20480, pre3 = 21504;
    const int relo[4] = {0, 524288, 655360, 688128};
    const float b2v = b2[0];
    const int px = lane & 31;
    const int kb = (lane >> 5) << 3;        // k sub-base within 16-chunk

    for (int T = blockIdx.x; T < 21760; T += gridDim.x) {
        int s = (T >= pre1) + (T >= pre2) + (T >= pre3);
        int t2 = T - ((s == 0) ? 0 : (s == 1) ? pre1 : (s == 2) ? pre2 : pre3);
        int Wd = 512 >> s, HW = Wd * Wd;
        int p0 = t2 * 32;                   // HW % 32 == 0 -> no b straddle
        int b = (p0 >= HW) ? 1 : 0;
        int pb = p0 - b * HW;
        const float* xp = fms[s] + (size_t)b * CH * HW + pb + px;
        int rr = Wd >> 6; if (rr < 1) rr = 1;

        f16v acc;
        #pragma unroll
        for (int q = 0; q < 16; ++q) acc[q] = 0.f;

        #define MFMA6(AH, AM, AL)                                                   \
            acc = __builtin_amdgcn_mfma_f32_32x32x16_bf16(AH, bh, acc, 0, 0, 0);    \
            acc = __builtin_amdgcn_mfma_f32_32x32x16_bf16(AH, bm, acc, 0, 0, 0);    \
            acc = __builtin_amdgcn_mfma_f32_32x32x16_bf16(AM, bh, acc, 0, 0, 0);    \
            acc = __builtin_amdgcn_mfma_f32_32x32x16_bf16(AM, bm, acc, 0, 0, 0);    \
            acc = __builtin_amdgcn_mfma_f32_32x32x16_bf16(AH, bl, acc, 0, 0, 0);    \
            acc = __builtin_amdgcn_mfma_f32_32x32x16_bf16(AL, bh, acc, 0, 0, 0);

        #pragma unroll 1   // REAL loop: prevents load hoisting -> no spill (R14)
        for (int kc = 0; kc < 8; ++kc) {
            float xv[8];
            #pragma unroll
            for (int e = 0; e < 8; ++e)
                xv[e] = xp[(size_t)(kc * 16 + kb + e) * HW];

            s8v bh, bm, bl;
            #pragma unroll
            for (int e = 0; e < 8; ++e) {
                unsigned short h, m, l;
                split3(xv[e], h, m, l);
                bh[e] = (short)h; bm[e] = (short)m; bl[e] = (short)l;
            }
            switch (kc) {
                case 0: MFMA6(a0h, a0m, a0l) break;
                case 1: MFMA6(a1h, a1m, a1l) break;
                case 2: MFMA6(a2h, a2m, a2l) break;
                case 3: MFMA6(a3h, a3m, a3l) break;
                case 4: MFMA6(a4h, a4m, a4l) break;
                case 5: MFMA6(a5h, a5m, a5l) break;
                case 6: MFMA6(a6h, a6m, a6l) break;
                default: MFMA6(a7h, a7m, a7l) break;
            }
        }
        #undef MFMA6

        // epilogue: partial over this wave's 32 och
        float part = 0.f;
        #pragma unroll
        for (int q = 0; q < 16; ++q) {
            int row = (q & 3) + ((q >> 2) << 3) + ((lane >> 5) << 2);
            int och = w * 32 + row;
            part += w2s[och] * gelu_exact(acc[q] + b1s[och]);
        }
        part += __shfl_xor(part, 32);       // merge the two row-halves per px
        if (lane < 32) partLds[w][lane] = part;
        __syncthreads();
        if (tid < 32) {                     // deterministic 4-way sum
            float tot = partLds[0][tid] + partLds[1][tid] +
                        partLds[2][tid] + partLds[3][tid] + b2v;
            int p = pb + tid;
            int y = p / Wd, x = p - y * Wd;
            bool inte = (y >= rr) && (y < Wd - rr) && (x >= rr) && (x < Wd - rr);
            rel[relo[s] + b * HW + p] = inte ? tot : NEG_INF;
        }
        __syncthreads();                    // protect partLds before next tile
    }
}

// ---------------- multi-scale NMS block decode (R23-verified) ----------------
__device__ __forceinline__ void nms_decode(int blk, int& s, int& b, int& ty, int& tx,
                                           int& Wd, int& HW, int& r, int& ro)
{
    s = (blk >= 512) + (blk >= 640) + (blk >= 672);
    int t2 = blk - ((s == 0) ? 0 : (s == 1) ? 512 : (s == 2) ? 640 : 672);
    Wd = 512 >> s; HW = Wd * Wd;
    int tpb = (Wd / TS) * (Wd / TS);
    b = t2 / tpb;
    int t = t2 - b * tpb;
    ty = t / (Wd / TS); tx = t - ty * (Wd / TS);
    r = Wd >> 6; if (r < 1) r = 1;
    ro = (s == 0) ? 0 : (s == 1) ? 524288 : (s == 2) ? 655360 : 688128;
}

__global__ __launch_bounds__(256) void nms_init_all(
    const float* __restrict__ rel, float* __restrict__ mask)
{
    int s, b, ty, tx, W, HW, r, ro;
    nms_decode(blockIdx.x, s, b, ty, tx, W, HW, r, ro);
    int H = W;
    int L = TS + 2 * r;
    __shared__ float wtile[48][49];
    __shared__ float t1[48][49];
    const float* wp = rel + ro + (size_t)b * HW;
    for (int idx = threadIdx.x; idx < L * L; idx += 256) {
        int i = idx / L, j = idx - i * L;
        int gy = min(max(ty * TS - r + i, 0), H - 1);
        int gx = min(max(tx * TS - r + j, 0), W - 1);
        wtile[i][j] = wp[gy * W + gx];
    }
    __syncthreads();
    for (int idx = threadIdx.x; idx < L * TS; idx += 256) {
        int i = idx / TS, j = idx - i * TS;
        float m = wtile[i][j];
        for (int d = 1; d <= 2 * r; ++d) m = fmaxf(m, wtile[i][j + d]);
        t1[i][j] = m;
    }
    __syncthreads();
    for (int idx = threadIdx.x; idx < TS * TS; idx += 256) {
        int i = idx / TS, j = idx - i * TS;
        float m = t1[i][j];
        for (int d = 1; d <= 2 * r; ++d) m = fmaxf(m, t1[i + d][j]);
        mask[ro + (size_t)b * HW + (ty * TS + i) * W + (tx * TS + j)] =
            (wtile[i + r][j + r] == m) ? 1.0f : 0.0f;
    }
}

__global__ __launch_bounds__(256) void nms_fused_all(
    const float* __restrict__ rel, float* __restrict__ mask, int do_compact,
    float* __restrict__ lval, int* __restrict__ lidx, int* __restrict__ counts)
{
    int s, b, ty, tx, W, HW, r, ro;
    nms_decode(blockIdx.x, s, b, ty, tx, W, HW, r, ro);
    int H = W;
    int L = TS + 4 * r;                 // <= 64
    int gy0 = ty * TS - 2 * r, gx0 = tx * TS - 2 * r;
    __shared__ float A[64][65], B[64][65], C[64][65];
    const float* mp = mask + ro + (size_t)b * HW;
    const float* rp = rel + ro + (size_t)b * HW;

    for (int idx = threadIdx.x; idx < L * L; idx += 256) {
        int i = idx / L, j = idx - i * L;
        int gy = min(max(gy0 + i, 0), H - 1);
        int gx = min(max(gx0 + j, 0), W - 1);
        A[i][j] = mp[gy * W + gx];
    }
    __syncthreads();
    int w1c = L - 2 * r;
    for (int idx = threadIdx.x; idx < L * w1c; idx += 256) {
        int i = idx / w1c, j = idx - i * w1c + r;
        float m = A[i][j - r];
        for (int d = 1; d <= 2 * r; ++d) m = fmaxf(m, A[i][j - r + d]);
        B[i][j] = m;
    }
    __syncthreads();
    for (int idx = threadIdx.x; idx < w1c * w1c; idx += 256) {
        int i = idx / w1c + r, j = idx % w1c + r;
        float m = B[i - r][j];
        for (int d = 1; d <= 2 * r; ++d) m = fmaxf(m, B[i - r + d][j]);
        C[i][j] = m;
    }
    float mreg[4];
    #pragma unroll
    for (int k = 0; k < 4; ++k) {
        int idx = threadIdx.x + k * 256;
        int i = idx >> 5, j = idx & 31;
        mreg[k] = A[2 * r + i][2 * r + j];
    }
    __syncthreads();
    for (int idx = threadIdx.x; idx < w1c * w1c; idx += 256) {
        int i = idx / w1c + r, j = idx % w1c + r;
        int gy = min(max(gy0 + i, 0), H - 1);
        int gx = min(max(gx0 + j, 0), W - 1);
        B[i][j] = (C[i][j] > 0.f) ? NEG_INF : rp[gy * W + gx];
    }
    __syncthreads();
    for (int idx = threadIdx.x; idx < w1c * TS; idx += 256) {
        int i = idx / TS + r, j = idx % TS + 2 * r;
        float m = B[i][j - r];
        for (int d = 1; d <= 2 * r; ++d) m = fmaxf(m, B[i][j - r + d]);
        A[i][j] = m;
    }
    __syncthreads();
    #pragma unroll
    for (int k = 0; k < 4; ++k) {
        int idx = threadIdx.x + k * 256;
        int i = idx >> 5, j = idx & 31;
        int ci = 2 * r + i, cj = 2 * r + j;
        float m = A[ci - r][cj];
        for (int d = 1; d <= 2 * r; ++d) m = fmaxf(m, A[ci - r + d][cj]);
        bool supp = C[ci][cj] > 0.f;
        bool newm = (B[ci][cj] == m) && !supp;
        bool fin = (mreg[k] > 0.f) || newm;
        int gy = ty * TS + i, gx = tx * TS + j;
        size_t g = ro + (size_t)b * HW + gy * W + gx;
        if (!do_compact) {
            mask[g] = fin ? 1.f : 0.f;
        } else if (fin) {
            float v = rp[gy * W + gx];
            if (!isinf(v)) {
                int bs = b * 4 + s;
                int slot = atomicAdd(&counts[bs], 1);
                if (slot < CAP) { lval[bs * CAP + slot] = v; lidx[bs * CAP + slot] = gy * W + gx; }
            }
        }
    }
}

// ---------------- per-(b,scale) bitonic sort + top-K ----------------
__global__ __launch_bounds__(1024) void sort_topk_kernel(
    const float* __restrict__ lval, const int* __restrict__ lidx,
    const int* __restrict__ counts, float* __restrict__ tv, int* __restrict__ ti)
{
    __shared__ float sv[CAP];
    __shared__ int   si[CAP];
    int bs = blockIdx.x;
    int M = counts[bs]; if (M > CAP) M = CAP;
    for (int i = threadIdx.x; i < CAP; i += 1024) {
        if (i < M) { sv[i] = lval[bs * CAP + i]; si[i] = lidx[bs * CAP + i]; }
        else       { sv[i] = NEG_INF;            si[i] = 0x7FFFFFFF; }
    }
    __syncthreads();
    for (int k = 2; k <= CAP; k <<= 1) {
        for (int j = k >> 1; j > 0; j >>= 1) {
            for (int t = threadIdx.x; t < CAP; t += 1024) {
                int p = t ^ j;
                if (p > t) {
                    float va = sv[t], vb = sv[p];
                    int   ia = si[t], ib = si[p];
                    bool aBefore = (va > vb) || (va == vb && ia < ib);
                    bool up = ((t & k) == 0);
                    if (up ? !aBefore : aBefore) {
                        sv[t] = vb; sv[p] = va; si[t] = ib; si[p] = ia;
                    }
                }
            }
            __syncthreads();
        }
    }
    for (int j = threadIdx.x; j < KSEL; j += 1024) {
        if (j < M) { tv[bs * KSEL + j] = sv[j]; ti[bs * KSEL + j] = si[j]; }
        else       { tv[bs * KSEL + j] = NEG_INF; ti[bs * KSEL + j] = j - M; }
    }
}

// ---------------- coords + reliability outputs ----------------
__global__ __launch_bounds__(256) void coords_kernel(
    const float* __restrict__ tv, const int* __restrict__ ti, float* __restrict__ out)
{
    int gid = blockIdx.x * blockDim.x + threadIdx.x;
    if (gid >= 8 * KSEL) return;
    int bs = gid / KSEL, k = gid - bs * KSEL;
    int b = bs >> 2, s = bs & 3;
    int W = 512 >> s;
    int idx = ti[gid];
    int y = idx / W, x = idx - y * W;
    float nx = (float)x / (float)(W - 1) * 2.0f - 1.0f;
    float ny = (float)y / (float)(W - 1) * 2.0f - 1.0f;
    int pos = s * KSEL + k;
    out[((size_t)b * TOT + pos) * 2 + 0] = nx;
    out[((size_t)b * TOT + pos) * 2 + 1] = ny;
    out[2 * TOT * 2 + (size_t)b * TOT + pos] = tv[gid];
}

// ---------------- gathered projection head + bilinear combine ----------------
__global__ __launch_bounds__(128) void feats_kernel(
    const float* __restrict__ fm0, const float* __restrict__ fm1,
    const float* __restrict__ fm2, const float* __restrict__ fm3,
    const float* __restrict__ w1, const float* __restrict__ b1,
    const float* __restrict__ w2, const float* __restrict__ b2,
    const int* __restrict__ ti, float* __restrict__ out)
{
    int blk = blockIdx.x;             // (b*4+s)*KSEL + k
    int bs = blk / KSEL, k = blk - bs * KSEL;
    int b = bs >> 2, s = bs & 3;
    int W = 512 >> s, H = W, HW = H * W;
    const float* fm = (s == 0) ? fm0 : (s == 1) ? fm1 : (s == 2) ? fm2 : fm3;

    int idx = ti[bs * KSEL + k];
    int yi0 = idx / W, xi0 = idx - yi0 * W;
    float nx = (float)xi0 / (float)(W - 1) * 2.0f - 1.0f;
    float ny = (float)yi0 / (float)(H - 1) * 2.0f - 1.0f;
    float ix = ((nx + 1.0f) * (float)W - 1.0f) * 0.5f;
    float iy = ((ny + 1.0f) * (float)H - 1.0f) * 0.5f;
    float x0 = floorf(ix), y0 = floorf(iy);
    float x1 = x0 + 1.0f,  y1 = y0 + 1.0f;
    float wx1 = ix - x0, wy1 = iy - y0;

    float xs[4]  = {x0, x1, x0, x1};
    float ysv[4] = {y0, y0, y1, y1};
    float wn[4]  = {(1.0f - wx1) * (1.0f - wy1), wx1 * (1.0f - wy1),
                    (1.0f - wx1) * wy1,          wx1 * wy1};
    int pix[4]; float wv[4];
    #pragma unroll
    for (int n = 0; n < 4; ++n) {
        bool valid = (xs[n] >= 0.0f) && (xs[n] <= (float)(W - 1)) &&
                     (ysv[n] >= 0.0f) && (ysv[n] <= (float)(H - 1));
        int xc = (int)fminf(fmaxf(xs[n], 0.0f), (float)(W - 1));
        int yc = (int)fminf(fmaxf(ysv[n], 0.0f), (float)(H - 1));
        pix[n] = yc * W + xc;
        wv[n] = valid ? wn[n] : 0.0f;
    }

    __shared__ float xls[4][CH];
    __shared__ float hmix[CH];
    int o = threadIdx.x;
    {
        const float* fb_ = fm + ((size_t)b * CH + o) * HW;
        #pragma unroll
        for (int n = 0; n < 4; ++n) xls[n][o] = fb_[pix[n]];
    }
    __syncthreads();

    float h0 = b1[o], h1 = h0, h2 = h0, h3 = h0;
    const float* wr = w1 + o * CH;
    for (int c = 0; c < CH; ++c) {
        float w = wr[c];
        h0 = fmaf(w, xls[0][c], h0);
        h1 = fmaf(w, xls[1][c], h1);
        h2 = fmaf(w, xls[2][c], h2);
        h3 = fmaf(w, xls[3][c], h3);
    }
    float wsum = wv[0] + wv[1] + wv[2] + wv[3];
    hmix[o] = wv[0] * gelu_exact(h0) + wv[1] * gelu_exact(h1) +
              wv[2] * gelu_exact(h2) + wv[3] * gelu_exact(h3);
    __syncthreads();

    float acc = b2[o] * wsum;
    const float* w2r = w2 + o * CH;
    for (int c = 0; c < CH; ++c) acc = fmaf(w2r[c], hmix[c], acc);
    out[2 * TOT * 2 + 2 * TOT + ((size_t)b * TOT + s * KSEL + k) * CH + o] = acc;
}

// ---------------- host ----------------
extern "C" void kernel_launch(void* const* d_in, const int* in_sizes, int n_in,
                              void* d_out, int out_size, void* d_ws, size_t ws_size,
                              hipStream_t stream)
{
    const float* fm[4] = {(const float*)d_in[0], (const float*)d_in[1],
                          (const float*)d_in[2], (const float*)d_in[3]};
    const float* rw1 = (const float*)d_in[4];
    const float* rb1 = (const float*)d_in[5];
    const float* rw2 = (const float*)d_in[6];
    const float* rb2 = (const float*)d_in[7];
    const float* fw1 = (const float*)d_in[8];
    const float* fb1 = (const float*)d_in[9];
    const float* fw2 = (const float*)d_in[10];
    const float* fb2 = (const float*)d_in[11];

    float* ws = (float*)d_ws;
    float* rel   = ws;                              // 696320 (all scales)
    float* mask  = ws + 696320;                     // 696320 (all scales)
    float* lval  = ws + 1392640;                    // 8*CAP
    int*   lidx  = (int*)(ws + 1425408);            // 8*CAP
    int*   counts= (int*)(ws + 1458176);            // 8
    float* tv    = ws + 1458184;                    // 8*KSEL
    int*   ti    = (int*)(ws + 1462280);            // 8*KSEL
    unsigned short* wfrag = (unsigned short*)(ws + 1466376); // 49152 u16

    hipMemsetAsync(counts, 0, 8 * sizeof(int), stream);
    wconv_kernel<<<64, 256, 0, stream>>>(rw1, wfrag);
    rel_mfma_kernel<<<768, 256, 0, stream>>>(fm[0], fm[1], fm[2], fm[3],
                                             wfrag, rb1, rw2, rb2, rel);

    nms_init_all<<<680, 256, 0, stream>>>(rel, mask);
    nms_fused_all<<<680, 256, 0, stream>>>(rel, mask, 0, lval, lidx, counts);
    nms_fused_all<<<680, 256, 0, stream>>>(rel, mask, 1, lval, lidx, counts);

    sort_topk_kernel<<<8, 1024, 0, stream>>>(lval, lidx, counts, tv, ti);
    coords_kernel<<<16, 256, 0, stream>>>(tv, ti, (float*)d_out);
    feats_kernel<<<4096, 128, 0, stream>>>(fm[0], fm[1], fm[2], fm[3],
                                           fw1, fb1, fw2, fb2, ti, (float*)d_out);
}

// Round 25
// 493.042 us; speedup vs baseline: 1.5935x; 1.5935x over previous
//
#include <hip/hip_runtime.h>
#include <hip/hip_bf16.h>
#include <math.h>

#define CH 128
#define KSEL 512
#define CAP 4096
#define TOT 2048   // 4*KSEL
#define TS 32      // NMS tile
#define NEG_INF (-__builtin_inff())

typedef short s8v __attribute__((ext_vector_type(8)));   // 8 bf16 (4 VGPRs)
typedef float f4v __attribute__((ext_vector_type(4)));   // MFMA acc

__device__ __forceinline__ float gelu_exact(float v) {
    return v * 0.5f * (1.0f + erff(v * 0.70710678118654752440f));
}

// exact 3-plane bf16 split via HW cvt (R23-verified): v = h + m + l + O(2^-24 v)
__device__ __forceinline__ void split3(float v, unsigned short& h,
                                       unsigned short& m, unsigned short& l)
{
    union BU { __hip_bfloat16 b; unsigned short u; };
    __hip_bfloat16 hb = __float2bfloat16(v);
    BU x; x.b = hb; h = x.u;
    float r1 = v - __bfloat162float(hb);
    __hip_bfloat16 mb = __float2bfloat16(r1);
    BU y; y.b = mb; m = y.u;
    float r2 = r1 - __bfloat162float(mb);
    __hip_bfloat16 lb = __float2bfloat16(r2);
    BU z; z.b = lb; l = z.u;
}

// ---------------- W1 -> 3-plane bf16 A-fragments (verified layout) ----------------
__global__ __launch_bounds__(256) void wconv_kernel(const float* __restrict__ w1,
                                                    unsigned short* __restrict__ wfrag)
{
    for (int e = blockIdx.x * 256 + threadIdx.x; e < 49152; e += gridDim.x * 256) {
        int fid = e >> 9;
        int r = e & 511;
        int lane = r >> 3;
        int el = r & 7;
        int plane = fid % 3;
        int fq = fid / 3;
        int kc = fq >> 3, ot = fq & 7;
        int och = ot * 16 + (lane & 15);
        int k = kc * 32 + ((lane >> 4) << 3) + el;
        unsigned short h, m, l;
        split3(w1[och * CH + k], h, m, l);
        wfrag[e] = (plane == 0) ? h : (plane == 1) ? m : l;
    }
}

// ---------------- reliability head via split-bf16 MFMA (R23-verified best) ----------
// Register-capped at 2 waves/SIMD (128 VGPR + 64 AGPR = 192/wave; pool=512/lane).
// R17-R21,R24 all regressed trying to escape this point (l-from-global, merged
// NMS, reg prefetch, 16-px waves, LDS staging, 32x32 W-in-regs) — keep as is.
__global__ __launch_bounds__(512) void rel_mfma_kernel(
    const float* __restrict__ fm0, const float* __restrict__ fm1,
    const float* __restrict__ fm2, const float* __restrict__ fm3,
    const unsigned short* __restrict__ wfrag,
    const float* __restrict__ b1, const float* __restrict__ w2,
    const float* __restrict__ b2, float* __restrict__ rel)
{
    __shared__ uint4 WfQ[6144];            // 96 KB W fragments
    __shared__ float w2s[128], b1s[128];
    unsigned short* Wf = (unsigned short*)WfQ;

    const int tid = threadIdx.x;
    {
        const uint4* src = (const uint4*)wfrag;
        for (int i = tid; i < 6144; i += 512) WfQ[i] = src[i];
    }
    if (tid < 128) { w2s[tid] = w2[tid]; b1s[tid] = b1[tid]; }
    __syncthreads();

    const float* fms[4] = {fm0, fm1, fm2, fm3};
    const int pre1 = 2048, pre2 = 2560, pre3 = 2688;
    const int relo[4] = {0, 524288, 655360, 688128};
    const float b2v = b2[0];

    const int lane = tid & 63;
    const int j = lane & 15;
    const int g8 = (lane >> 4) << 3;
    const int w = tid >> 6;

    for (int T = blockIdx.x; T < 2720; T += gridDim.x) {
        int s = (T >= pre1) + (T >= pre2) + (T >= pre3);
        int t2 = T - ((s == 0) ? 0 : (s == 1) ? pre1 : (s == 2) ? pre2 : pre3);
        int Wd = 512 >> s, HW = Wd * Wd;
        int p0 = t2 * 256 + w * 32;
        int b = (p0 >= HW) ? 1 : 0;
        int pb = p0 - b * HW;
        const float* fp = fms[s] + (size_t)b * CH * HW;
        int rr = Wd >> 6; if (rr < 1) rr = 1;

        const float* pxp = fp + pb + 2 * j;

        f4v acc[8][2];
        #pragma unroll
        for (int ot = 0; ot < 8; ++ot)
            #pragma unroll
            for (int st = 0; st < 2; ++st) {
                acc[ot][st][0] = 0.f; acc[ot][st][1] = 0.f;
                acc[ot][st][2] = 0.f; acc[ot][st][3] = 0.f;
            }

        #pragma unroll 1   // REAL loop: prevents load hoisting -> no spill (R14)
        for (int kc = 0; kc < 4; ++kc) {
            float2 xv[8];
            #pragma unroll
            for (int e = 0; e < 8; ++e)
                xv[e] = *(const float2*)(pxp + (size_t)(kc * 32 + g8 + e) * HW);

            s8v bh0, bm0, bl0, bh1, bm1, bl1;
            #pragma unroll
            for (int e = 0; e < 8; ++e) {
                unsigned short h, m, l;
                split3(xv[e].x, h, m, l);
                bh0[e] = (short)h; bm0[e] = (short)m; bl0[e] = (short)l;
                split3(xv[e].y, h, m, l);
                bh1[e] = (short)h; bm1[e] = (short)m; bl1[e] = (short)l;
            }
            #pragma unroll
            for (int ot = 0; ot < 8; ++ot) {
                const unsigned short* fb = Wf + (((kc << 3) + ot) * 3) * 512 + (lane << 3);
                s8v ah = *(const s8v*)fb;
                s8v am = *(const s8v*)(fb + 512);
                s8v al = *(const s8v*)(fb + 1024);
                acc[ot][0] = __builtin_amdgcn_mfma_f32_16x16x32_bf16(ah, bh0, acc[ot][0], 0, 0, 0);
                acc[ot][0] = __builtin_amdgcn_mfma_f32_16x16x32_bf16(ah, bm0, acc[ot][0], 0, 0, 0);
                acc[ot][0] = __builtin_amdgcn_mfma_f32_16x16x32_bf16(am, bh0, acc[ot][0], 0, 0, 0);
                acc[ot][0] = __builtin_amdgcn_mfma_f32_16x16x32_bf16(am, bm0, acc[ot][0], 0, 0, 0);
                acc[ot][0] = __builtin_amdgcn_mfma_f32_16x16x32_bf16(ah, bl0, acc[ot][0], 0, 0, 0);
                acc[ot][0] = __builtin_amdgcn_mfma_f32_16x16x32_bf16(al, bh0, acc[ot][0], 0, 0, 0);
                acc[ot][1] = __builtin_amdgcn_mfma_f32_16x16x32_bf16(ah, bh1, acc[ot][1], 0, 0, 0);
                acc[ot][1] = __builtin_amdgcn_mfma_f32_16x16x32_bf16(ah, bm1, acc[ot][1], 0, 0, 0);
                acc[ot][1] = __builtin_amdgcn_mfma_f32_16x16x32_bf16(am, bh1, acc[ot][1], 0, 0, 0);
                acc[ot][1] = __builtin_amdgcn_mfma_f32_16x16x32_bf16(am, bm1, acc[ot][1], 0, 0, 0);
                acc[ot][1] = __builtin_amdgcn_mfma_f32_16x16x32_bf16(ah, bl1, acc[ot][1], 0, 0, 0);
                acc[ot][1] = __builtin_amdgcn_mfma_f32_16x16x32_bf16(al, bh1, acc[ot][1], 0, 0, 0);
            }
        }

        // epilogue: C/D map (HW-verified): col = lane&15, row = (lane>>4)*4 + r
        float part0 = 0.f, part1 = 0.f;
        #pragma unroll
        for (int ot = 0; ot < 8; ++ot) {
            #pragma unroll
            for (int r = 0; r < 4; ++r) {
                int och = ot * 16 + ((lane >> 4) << 2) + r;
                float wv = w2s[och], bv = b1s[och];
                part0 += wv * gelu_exact(acc[ot][0][r] + bv);
                part1 += wv * gelu_exact(acc[ot][1][r] + bv);
            }
        }
        part0 += __shfl_xor(part0, 16);
        part0 += __shfl_xor(part0, 32);
        part1 += __shfl_xor(part1, 16);
        part1 += __shfl_xor(part1, 32);
        if (lane < 16) {
            int p0x = pb + 2 * lane;
            int y0 = p0x / Wd, x0 = p0x - y0 * Wd;
            int p1x = p0x + 1;
            int y1 = p1x / Wd, x1 = p1x - y1 * Wd;
            bool in0 = (y0 >= rr) && (y0 < Wd - rr) && (x0 >= rr) && (x0 < Wd - rr);
            bool in1 = (y1 >= rr) && (y1 < Wd - rr) && (x1 >= rr) && (x1 < Wd - rr);
            float2 o;
            o.x = in0 ? (part0 + b2v) : NEG_INF;
            o.y = in1 ? (part1 + b2v) : NEG_INF;
            *(float2*)&rel[relo[s] + b * HW + p0x] = o;
        }
    }
}

// ---------------- multi-scale NMS block decode ----------------
// tiles/scale: s0 512, s1 128, s2 32, s3 8 -> 680 blocks per stage
__device__ __forceinline__ void nms_decode(int blk, int& s, int& b, int& ty, int& tx,
                                           int& Wd, int& HW, int& r, int& ro)
{
    s = (blk >= 512) + (blk >= 640) + (blk >= 672);
    int t2 = blk - ((s == 0) ? 0 : (s == 1) ? 512 : (s == 2) ? 640 : 672);
    Wd = 512 >> s; HW = Wd * Wd;
    int tpb = (Wd / TS) * (Wd / TS);
    b = t2 / tpb;
    int t = t2 - b * tpb;
    ty = t / (Wd / TS); tx = t - ty * (Wd / TS);
    r = Wd >> 6; if (r < 1) r = 1;
    ro = (s == 0) ? 0 : (s == 1) ? 524288 : (s == 2) ? 655360 : 688128;
}

// init: mask = (rel == maxpool_r(rel))  [R16-verified]
__global__ __launch_bounds__(256) void nms_init_all(
    const float* __restrict__ rel, float* __restrict__ mask)
{
    int s, b, ty, tx, W, HW, r, ro;
    nms_decode(blockIdx.x, s, b, ty, tx, W, HW, r, ro);
    int H = W;
    int L = TS + 2 * r;
    __shared__ float wtile[48][49];
    __shared__ float t1[48][49];
    const float* wp = rel + ro + (size_t)b * HW;
    for (int idx = threadIdx.x; idx < L * L; idx += 256) {
        int i = idx / L, j = idx - i * L;
        int gy = min(max(ty * TS - r + i, 0), H - 1);
        int gx = min(max(tx * TS - r + j, 0), W - 1);
        wtile[i][j] = wp[gy * W + gx];
    }
    __syncthreads();
    for (int idx = threadIdx.x; idx < L * TS; idx += 256) {
        int i = idx / TS, j = idx - i * TS;
        float m = wtile[i][j];
        for (int d = 1; d <= 2 * r; ++d) m = fmaxf(m, wtile[i][j + d]);
        t1[i][j] = m;
    }
    __syncthreads();
    for (int idx = threadIdx.x; idx < TS * TS; idx += 256) {
        int i = idx / TS, j = idx - i * TS;
        float m = t1[i][j];
        for (int d = 1; d <= 2 * r; ++d) m = fmaxf(m, t1[i + d][j]);
        mask[ro + (size_t)b * HW + (ty * TS + i) * W + (tx * TS + j)] =
            (wtile[i + r][j + r] == m) ? 1.0f : 0.0f;
    }
}

// fused iterA+iterB (R16-verified); optional compact
__global__ __launch_bounds__(256) void nms_fused_all(
    const float* __restrict__ rel, float* __restrict__ mask, int do_compact,
    float* __restrict__ lval, int* __restrict__ lidx, int* __restrict__ counts)
{
    int s, b, ty, tx, W, HW, r, ro;
    nms_decode(blockIdx.x, s, b, ty, tx, W, HW, r, ro);
    int H = W;
    int L = TS + 4 * r;                 // <= 64
    int gy0 = ty * TS - 2 * r, gx0 = tx * TS - 2 * r;
    __shared__ float A[64][65], B[64][65], C[64][65];
    const float* mp = mask + ro + (size_t)b * HW;
    const float* rp = rel + ro + (size_t)b * HW;

    for (int idx = threadIdx.x; idx < L * L; idx += 256) {
        int i = idx / L, j = idx - i * L;
        int gy = min(max(gy0 + i, 0), H - 1);
        int gx = min(max(gx0 + j, 0), W - 1);
        A[i][j] = mp[gy * W + gx];
    }
    __syncthreads();
    int w1c = L - 2 * r;
    for (int idx = threadIdx.x; idx < L * w1c; idx += 256) {
        int i = idx / w1c, j = idx - i * w1c + r;
        float m = A[i][j - r];
        for (int d = 1; d <= 2 * r; ++d) m = fmaxf(m, A[i][j - r + d]);
        B[i][j] = m;
    }
    __syncthreads();
    for (int idx = threadIdx.x; idx < w1c * w1c; idx += 256) {
        int i = idx / w1c + r, j = idx % w1c + r;
        float m = B[i - r][j];
        for (int d = 1; d <= 2 * r; ++d) m = fmaxf(m, B[i - r + d][j]);
        C[i][j] = m;
    }
    float mreg[4];
    #pragma unroll
    for (int k = 0; k < 4; ++k) {
        int idx = threadIdx.x + k * 256;
        int i = idx >> 5, j = idx & 31;
        mreg[k] = A[2 * r + i][2 * r + j];
    }
    __syncthreads();
    for (int idx = threadIdx.x; idx < w1c * w1c; idx += 256) {
        int i = idx / w1c + r, j = idx % w1c + r;
        int gy = min(max(gy0 + i, 0), H - 1);
        int gx = min(max(gx0 + j, 0), W - 1);
        B[i][j] = (C[i][j] > 0.f) ? NEG_INF : rp[gy * W + gx];
    }
    __syncthreads();
    for (int idx = threadIdx.x; idx < w1c * TS; idx += 256) {
        int i = idx / TS + r, j = idx % TS + 2 * r;
        float m = B[i][j - r];
        for (int d = 1; d <= 2 * r; ++d) m = fmaxf(m, B[i][j - r + d]);
        A[i][j] = m;
    }
    __syncthreads();
    #pragma unroll
    for (int k = 0; k < 4; ++k) {
        int idx = threadIdx.x + k * 256;
        int i = idx >> 5, j = idx & 31;
        int ci = 2 * r + i, cj = 2 * r + j;
        float m = A[ci - r][cj];
        for (int d = 1; d <= 2 * r; ++d) m = fmaxf(m, A[ci - r + d][cj]);
        bool supp = C[ci][cj] > 0.f;
        bool newm = (B[ci][cj] == m) && !supp;
        bool fin = (mreg[k] > 0.f) || newm;
        int gy = ty * TS + i, gx = tx * TS + j;
        size_t g = ro + (size_t)b * HW + gy * W + gx;
        if (!do_compact) {
            mask[g] = fin ? 1.f : 0.f;
        } else if (fin) {
            float v = rp[gy * W + gx];
            if (!isinf(v)) {
                int bs = b * 4 + s;
                int slot = atomicAdd(&counts[bs], 1);
                if (slot < CAP) { lval[bs * CAP + slot] = v; lidx[bs * CAP + slot] = gy * W + gx; }
            }
        }
    }
}

// ---------------- per-(b,scale) bitonic sort + top-K ----------------
__global__ __launch_bounds__(1024) void sort_topk_kernel(
    const float* __restrict__ lval, const int* __restrict__ lidx,
    const int* __restrict__ counts, float* __restrict__ tv, int* __restrict__ ti)
{
    __shared__ float sv[CAP];
    __shared__ int   si[CAP];
    int bs = blockIdx.x;
    int M = counts[bs]; if (M > CAP) M = CAP;
    for (int i = threadIdx.x; i < CAP; i += 1024) {
        if (i < M) { sv[i] = lval[bs * CAP + i]; si[i] = lidx[bs * CAP + i]; }
        else       { sv[i] = NEG_INF;            si[i] = 0x7FFFFFFF; }
    }
    __syncthreads();
    for (int k = 2; k <= CAP; k <<= 1) {
        for (int j = k >> 1; j > 0; j >>= 1) {
            for (int t = threadIdx.x; t < CAP; t += 1024) {
                int p = t ^ j;
                if (p > t) {
                    float va = sv[t], vb = sv[p];
                    int   ia = si[t], ib = si[p];
                    bool aBefore = (va > vb) || (va == vb && ia < ib);
                    bool up = ((t & k) == 0);
                    if (up ? !aBefore : aBefore) {
                        sv[t] = vb; sv[p] = va; si[t] = ib; si[p] = ia;
                    }
                }
            }
            __syncthreads();
        }
    }
    for (int j = threadIdx.x; j < KSEL; j += 1024) {
        if (j < M) { tv[bs * KSEL + j] = sv[j]; ti[bs * KSEL + j] = si[j]; }
        else       { tv[bs * KSEL + j] = NEG_INF; ti[bs * KSEL + j] = j - M; }
    }
}

// ---------------- coords + reliability outputs ----------------
__global__ __launch_bounds__(256) void coords_kernel(
    const float* __restrict__ tv, const int* __restrict__ ti, float* __restrict__ out)
{
    int gid = blockIdx.x * blockDim.x + threadIdx.x;
    if (gid >= 8 * KSEL) return;
    int bs = gid / KSEL, k = gid - bs * KSEL;
    int b = bs >> 2, s = bs & 3;
    int W = 512 >> s;
    int idx = ti[gid];
    int y = idx / W, x = idx - y * W;
    float nx = (float)x / (float)(W - 1) * 2.0f - 1.0f;
    float ny = (float)y / (float)(W - 1) * 2.0f - 1.0f;
    int pos = s * KSEL + k;
    out[((size_t)b * TOT + pos) * 2 + 0] = nx;
    out[((size_t)b * TOT + pos) * 2 + 1] = ny;
    out[2 * TOT * 2 + (size_t)b * TOT + pos] = tv[gid];
}

// ---------------- gathered projection head + bilinear combine ----------------
__global__ __launch_bounds__(128) void feats_kernel(
    const float* __restrict__ fm0, const float* __restrict__ fm1,
    const float* __restrict__ fm2, const float* __restrict__ fm3,
    const float* __restrict__ w1, const float* __restrict__ b1,
    const float* __restrict__ w2, const float* __restrict__ b2,
    const int* __restrict__ ti, float* __restrict__ out)
{
    int blk = blockIdx.x;             // (b*4+s)*KSEL + k
    int bs = blk / KSEL, k = blk - bs * KSEL;
    int b = bs >> 2, s = bs & 3;
    int W = 512 >> s, H = W, HW = H * W;
    const float* fm = (s == 0) ? fm0 : (s == 1) ? fm1 : (s == 2) ? fm2 : fm3;

    int idx = ti[bs * KSEL + k];
    int yi0 = idx / W, xi0 = idx - yi0 * W;
    float nx = (float)xi0 / (float)(W - 1) * 2.0f - 1.0f;
    float ny = (float)yi0 / (float)(H - 1) * 2.0f - 1.0f;
    float ix = ((nx + 1.0f) * (float)W - 1.0f) * 0.5f;
    float iy = ((ny + 1.0f) * (float)H - 1.0f) * 0.5f;
    float x0 = floorf(ix), y0 = floorf(iy);
    float x1 = x0 + 1.0f,  y1 = y0 + 1.0f;
    float wx1 = ix - x0, wy1 = iy - y0;

    float xs[4]  = {x0, x1, x0, x1};
    float ysv[4] = {y0, y0, y1, y1};
    float wn[4]  = {(1.0f - wx1) * (1.0f - wy1), wx1 * (1.0f - wy1),
                    (1.0f - wx1) * wy1,          wx1 * wy1};
    int pix[4]; float wv[4];
    #pragma unroll
    for (int n = 0; n < 4; ++n) {
        bool valid = (xs[n] >= 0.0f) && (xs[n] <= (float)(W - 1)) &&
                     (ysv[n] >= 0.0f) && (ysv[n] <= (float)(H - 1));
        int xc = (int)fminf(fmaxf(xs[n], 0.0f), (float)(W - 1));
        int yc = (int)fminf(fmaxf(ysv[n], 0.0f), (float)(H - 1));
        pix[n] = yc * W + xc;
        wv[n] = valid ? wn[n] : 0.0f;
    }

    __shared__ float xls[4][CH];
    __shared__ float hmix[CH];
    int o = threadIdx.x;
    {
        const float* fb_ = fm + ((size_t)b * CH + o) * HW;
        #pragma unroll
        for (int n = 0; n < 4; ++n) xls[n][o] = fb_[pix[n]];
    }
    __syncthreads();

    float h0 = b1[o], h1 = h0, h2 = h0, h3 = h0;
    const float* wr = w1 + o * CH;
    for (int c = 0; c < CH; ++c) {
        float w = wr[c];
        h0 = fmaf(w, xls[0][c], h0);
        h1 = fmaf(w, xls[1][c], h1);
        h2 = fmaf(w, xls[2][c], h2);
        h3 = fmaf(w, xls[3][c], h3);
    }
    float wsum = wv[0] + wv[1] + wv[2] + wv[3];
    hmix[o] = wv[0] * gelu_exact(h0) + wv[1] * gelu_exact(h1) +
              wv[2] * gelu_exact(h2) + wv[3] * gelu_exact(h3);
    __syncthreads();

    float acc = b2[o] * wsum;
    const float* w2r = w2 + o * CH;
    for (int c = 0; c < CH; ++c) acc = fmaf(w2r[c], hmix[c], acc);
    out[2 * TOT * 2 + 2 * TOT + ((size_t)b * TOT + s * KSEL + k) * CH + o] = acc;
}

// ---------------- host ----------------
extern "C" void kernel_launch(void* const* d_in, const int* in_sizes, int n_in,
                              void* d_out, int out_size, void* d_ws, size_t ws_size,
                              hipStream_t stream)
{
    const float* fm[4] = {(const float*)d_in[0], (const float*)d_in[1],
                          (const float*)d_in[2], (const float*)d_in[3]};
    const float* rw1 = (const float*)d_in[4];
    const float* rb1 = (const float*)d_in[5];
    const float* rw2 = (const float*)d_in[6];
    const float* rb2 = (const float*)d_in[7];
    const float* fw1 = (const float*)d_in[8];
    const float* fb1 = (const float*)d_in[9];
    const float* fw2 = (const float*)d_in[10];
    const float* fb2 = (const float*)d_in[11];

    float* ws = (float*)d_ws;
    float* rel   = ws;                              // 696320 (all scales)
    float* mask  = ws + 696320;                     // 696320 (all scales)
    float* lval  = ws + 1392640;                    // 8*CAP
    int*   lidx  = (int*)(ws + 1425408);            // 8*CAP
    int*   counts= (int*)(ws + 1458176);            // 8
    float* tv    = ws + 1458184;                    // 8*KSEL
    int*   ti    = (int*)(ws + 1462280);            // 8*KSEL
    unsigned short* wfrag = (unsigned short*)(ws + 1466376); // 49152 u16

    hipMemsetAsync(counts, 0, 8 * sizeof(int), stream);
    wconv_kernel<<<64, 256, 0, stream>>>(rw1, wfrag);
    rel_mfma_kernel<<<256, 512, 0, stream>>>(fm[0], fm[1], fm[2], fm[3],
                                             wfrag, rb1, rw2, rb2, rel);

    nms_init_all<<<680, 256, 0, stream>>>(rel, mask);
    nms_fused_all<<<680, 256, 0, stream>>>(rel, mask, 0, lval, lidx, counts);
    nms_fused_all<<<680, 256, 0, stream>>>(rel, mask, 1, lval, lidx, counts);

    sort_topk_kernel<<<8, 1024, 0, stream>>>(lval, lidx, counts, tv, ti);
    coords_kernel<<<16, 256, 0, stream>>>(tv, ti, (float*)d_out);
    feats_kernel<<<4096, 128, 0, stream>>>(fm[0], fm[1], fm[2], fm[3],
                                           fw1, fb1, fw2, fb2, ti, (float*)d_out);
}